// Round 5
// baseline (1941.313 us; speedup 1.0000x reference)
//
#include <hip/hip_runtime.h>

// BiLSTM + partial-CRF loss, MI355X (gfx950).
// R12: pipelined canary sync. R11 proved the canary protocol (poll the data
// itself, coalesced b128 sc0 sc1) at 965us; its remaining 3300 cy/step of
// wait = first-poll flight on the critical path + serial retry quantization
// + two barrier-drains. R12:
//  (1) EARLY-ISSUE: next step's poll burst S1 is issued in the TAIL, right
//      after our own h store. All slices store at ~same phase, so S1's MALL
//      sample (~issue+RT/2) lands at peers' commit. Head = vmcnt(0) + check;
//      steady state: data already in regs (removes ~RT from the chain).
//      Retry fallback = R11's serial loop (budget 4096 -> NaN-visible fail).
//  (2) x-fragments for step it+1 prefetched in the tail (post-barrier).
//  (3) pre4 double-buffered (2x16KB LDS) -> ONE __syncthreads per step
//      (each barrier costs an implicit vmcnt(0) drain). WAR-safe: a wave
//      re-writes buffer p only after passing the next barrier, which all
//      waves reach only after finishing their reads of p.
// Only vmcnt(0) waits (no in-order counted-vmcnt assumptions); all polled
// values are asm-tied ("+v") so consumers can't hoist above the wait.
// k_crf: R8's register-resident rewrite (validated, absmax 0).
//
// Sizes: B=64, L=512, V=50000, E=256, H=512, T=32.
// Workspace (~84 MiB):
//   x2   bf16 [512*64][256]                16777216 B @ 0
//   H2   bf16 blocked [t][d][g][s][256]    67108864 B @ 16777216
//   em   f32  [512*64][32]                  4194304 B @ 83886080

#define IMPOSSIBLE -10000.0f
#define CANARY 0x7FFF7FFFu

typedef __attribute__((ext_vector_type(8))) short bf16x8;
typedef __attribute__((ext_vector_type(4))) float f32x4;
typedef __attribute__((ext_vector_type(4))) unsigned int u32x4;
typedef unsigned int u32;
typedef unsigned short u16;

__device__ __forceinline__ u16 f2b(float f) {           // fp32 -> bf16 (RNE)
  union { float f; u32 u; } v; v.f = f;
  return (u16)((v.u + 0x7fffu + ((v.u >> 16) & 1u)) >> 16);
}
__device__ __forceinline__ float sigm(float x) { return 1.0f / (1.0f + __expf(-x)); }
__device__ __forceinline__ float tanh_f(float x) { return 1.0f - 2.0f / (__expf(2.0f * x) + 1.0f); }

__device__ __forceinline__ u32 can4(const u32x4& q) {
  return (u32)(q[0] == CANARY) | (u32)(q[1] == CANARY) |
         (u32)(q[2] == CANARY) | (u32)(q[3] == CANARY);
}

// ---------------------------------------------------------------------------
// Canary-fill H2 with PLAIN dwordx4 stores (dispatch-end flush publishes to
// MALL -- same cross-dispatch path x2 uses; R11-proven). out=0.
__global__ __launch_bounds__(256) void k_init(u32* __restrict__ H2w,
                                              float* __restrict__ out) {
  const size_t i = ((size_t)blockIdx.x * 256 + threadIdx.x) * 4;
  const uint4 c4 = {CANARY, CANARY, CANARY, CANARY};
  *(uint4*)(H2w + i) = c4;
  if (blockIdx.x == 0 && threadIdx.x == 0)
    __hip_atomic_store((u32*)out, 0u, __ATOMIC_RELAXED, __HIP_MEMORY_SCOPE_AGENT);
}

// ---------------------------------------------------------------------------
// x2[t*64+b][e] = bf16(emb[sents[b][t]][e]).  One block per t.
__global__ __launch_bounds__(256) void k_embed(
    const int* __restrict__ sents, const float* __restrict__ emb,
    u16* __restrict__ x2) {
  __shared__ int tok[64];
  const int tid = threadIdx.x, t = blockIdx.x;
  if (tid < 64) tok[tid] = sents[tid * 512 + t];
  __syncthreads();
#pragma unroll
  for (int i = 0; i < 16; ++i) {
    const int v = i * 256 + tid;          // float4 index
    const int row = v >> 6, ke = (v & 63) * 4;
    const float4 f = *(const float4*)(emb + (size_t)tok[row] * 256 + ke);
    ushort4 s; s.x = f2b(f.x); s.y = f2b(f.y); s.z = f2b(f.z); s.w = f2b(f.w);
    *(ushort4*)&x2[((size_t)t * 64 + row) * 256 + ke] = s;
  }
}

// ---------------------------------------------------------------------------
// Persistent BiLSTM. 256 wgs x 256 thr, 1 wg/CU. group r=wid&7 -> (d=r>>2,
// g=r&3); slice s=wid>>3 (j0=s*16). Wave wv owns K-quarter for ALL 4 gates.
// Per step: x MFMAs (xcur from prev tail) -> vmcnt(0)+check S1 (issued prev
// tail; usually already valid) -> retry loop if needed -> h MFMAs ->
// ds_write pre4[buf] -> ONE barrier -> prefetch next x -> reduce + gates ->
// packed agent h store -> issue S1 for next step -> flip buf.
__global__ __launch_bounds__(256, 1) void k_lstm(
    const float* __restrict__ Whf, const float* __restrict__ Whb,
    const float* __restrict__ Wif, const float* __restrict__ Wib,
    const float* __restrict__ bf_, const float* __restrict__ bb_,
    const u16* __restrict__ x2, u16* __restrict__ H2) {
  __shared__ float pre4[2][4096];       // double-buffered [wv][gate][kh][lm][rr]
  const int tid = threadIdx.x, wid = blockIdx.x;
  const int r = wid & 7, d = r >> 2, g = r & 3, s = wid >> 3;
  const int b0 = g * 16, j0 = s * 16;
  const float* __restrict__ Whh = d ? Whb : Whf;
  const float* __restrict__ Wih = d ? Wib : Wif;
  const float* __restrict__ bias = d ? bb_ : bf_;
  const int wv = tid >> 6, lane = tid & 63, lm = lane & 15, kh = lane >> 4;
  const int bl = tid >> 4, jj = tid & 15;

  // ---- weight fragments: B[k][n], n=lane&15, k = kh*8+j + 32*kt + wv*Kq ----
  bf16x8 wih_f[8], whh_f[16];
#pragma unroll
  for (int gg = 0; gg < 4; ++gg) {
    const float* wp = Wih + (size_t)(gg * 512 + j0 + lm) * 256 + wv * 64;
#pragma unroll
    for (int kt = 0; kt < 2; ++kt) {
      bf16x8 f;
#pragma unroll
      for (int j = 0; j < 8; ++j) f[j] = (short)f2b(wp[kt * 32 + kh * 8 + j]);
      wih_f[gg * 2 + kt] = f;
    }
    const float* wq = Whh + (size_t)(gg * 512 + j0 + lm) * 512 + wv * 128;
#pragma unroll
    for (int kt = 0; kt < 4; ++kt) {
      bf16x8 f;
#pragma unroll
      for (int j = 0; j < 8; ++j) f[j] = (short)f2b(wq[kt * 32 + kh * 8 + j]);
      whh_f[gg * 4 + kt] = f;
    }
  }
  const float b_i = bias[0 * 512 + j0 + jj];
  const float b_f = bias[1 * 512 + j0 + jj];
  const float b_g = bias[2 * 512 + j0 + jj];
  const float b_o = bias[3 * 512 + j0 + jj];

  float c = 0.f;
  const f32x4 z = {0.f, 0.f, 0.f, 0.f};
  int buf = 0;

  // prologue: x fragments for it=0
  bf16x8 xc0, xc1;
  {
    const int tt0 = d ? 511 : 0;
    const u16* xp = x2 + ((size_t)tt0 * 64 + b0 + lm) * 256 + wv * 64 + kh * 8;
    xc0 = *(const bf16x8*)xp;
    xc1 = *(const bf16x8*)(xp + 32);
  }
  u32x4 q0 = {0, 0, 0, 0}, q1 = {0, 0, 0, 0}, q2 = {0, 0, 0, 0}, q3 = {0, 0, 0, 0};
  const u32 *p0 = nullptr, *p1 = nullptr, *p2 = nullptr, *p3 = nullptr;

#pragma unroll 1
  for (int it = 0; it < 512; ++it) {
    const int tt = d ? (511 - it) : it;
    f32x4 accg[4] = {z, z, z, z};
    // x MFMAs first: fills the (usually zero) residual wait on S1
#pragma unroll
    for (int gg = 0; gg < 4; ++gg) {
      accg[gg] = __builtin_amdgcn_mfma_f32_16x16x32_bf16(xc0, wih_f[gg * 2 + 0], accg[gg], 0, 0, 0);
      accg[gg] = __builtin_amdgcn_mfma_f32_16x16x32_bf16(xc1, wih_f[gg * 2 + 1], accg[gg], 0, 0, 0);
    }
    if (it > 0) {
      // S1 was issued in the previous tail; drain + check (tied regs)
      asm volatile("s_waitcnt vmcnt(0)"
                   : "+v"(q0), "+v"(q1), "+v"(q2), "+v"(q3) :: "memory");
      u32 anybad = can4(q0) | can4(q1) | can4(q2) | can4(q3);
      int bud = 4096;       // on exhaust: canary NaNs propagate -> absmax fail
      while (__any(anybad != 0) && --bud) {
        asm volatile(
            "global_load_dwordx4 %0, %4, off sc0 sc1\n\t"
            "global_load_dwordx4 %1, %5, off sc0 sc1\n\t"
            "global_load_dwordx4 %2, %6, off sc0 sc1\n\t"
            "global_load_dwordx4 %3, %7, off sc0 sc1\n\t"
            "s_waitcnt vmcnt(0)"
            : "=&v"(q0), "=&v"(q1), "=&v"(q2), "=&v"(q3)
            : "v"(p0), "v"(p1), "v"(p2), "v"(p3)
            : "memory");
        anybad = can4(q0) | can4(q1) | can4(q2) | can4(q3);
      }
      union { u32x4 q; bf16x8 v; } c0, c1, c2, c3;
      c0.q = q0; c1.q = q1; c2.q = q2; c3.q = q3;
#pragma unroll
      for (int gg = 0; gg < 4; ++gg) {
        accg[gg] = __builtin_amdgcn_mfma_f32_16x16x32_bf16(c0.v, whh_f[gg * 4 + 0], accg[gg], 0, 0, 0);
        accg[gg] = __builtin_amdgcn_mfma_f32_16x16x32_bf16(c1.v, whh_f[gg * 4 + 1], accg[gg], 0, 0, 0);
        accg[gg] = __builtin_amdgcn_mfma_f32_16x16x32_bf16(c2.v, whh_f[gg * 4 + 2], accg[gg], 0, 0, 0);
        accg[gg] = __builtin_amdgcn_mfma_f32_16x16x32_bf16(c3.v, whh_f[gg * 4 + 3], accg[gg], 0, 0, 0);
      }
    }
    // partials -> LDS buf, one ds_write_b128 per gate
#pragma unroll
    for (int gg = 0; gg < 4; ++gg)
      *(f32x4*)&pre4[buf][wv * 1024 + gg * 256 + kh * 64 + lm * 4] = accg[gg];
    __syncthreads();        // the ONE barrier per step (RAW for pre4[buf])
    if (it < 511) {         // prefetch x for it+1 (in flight through tail)
      const int ttn = d ? (tt - 1) : (tt + 1);
      const u16* xp = x2 + ((size_t)ttn * 64 + b0 + lm) * 256 + wv * 64 + kh * 8;
      xc0 = *(const bf16x8*)xp;
      xc1 = *(const bf16x8*)(xp + 32);
    }
    const int off = (bl >> 2) * 64 + jj * 4 + (bl & 3);
    float pi = b_i, pf = b_f, pg = b_g, po = b_o;
#pragma unroll
    for (int w4 = 0; w4 < 4; ++w4) {
      pi += pre4[buf][w4 * 1024 + 0   + off];
      pf += pre4[buf][w4 * 1024 + 256 + off];
      pg += pre4[buf][w4 * 1024 + 512 + off];
      po += pre4[buf][w4 * 1024 + 768 + off];
    }
    c = sigm(pf) * c + sigm(pi) * tanh_f(pg);
    const float h = sigm(po) * tanh_f(c);
    const float hq = __shfl_xor(h, 1);
    if ((tid & 1) == 0) {   // block element = tid; pack pair -> u32, agent store
      const u32 pk = (u32)f2b(h) | ((u32)f2b(hq) << 16);
      u32* hp2 = (u32*)H2 + ((((size_t)tt * 2 + d) * 4 + g) * 32 + s) * 128 + (tid >> 1);
      __hip_atomic_store(hp2, pk, __ATOMIC_RELAXED, __HIP_MEMORY_SCOPE_AGENT);
    }
    if (it < 511) {
      // EARLY-ISSUE S1 for it+1: sources = h[tt] (tp(it+1) == tt, both dirs).
      // Issued after our store; sampled ~RT/2 later == peers' commit time.
      const size_t tb2 = (((size_t)tt * 2 + d) * 4 + g) * 32;
      const int fo = lm * 16 + (kh & 1) * 8;
      p0 = (const u32*)(H2 + (tb2 + wv * 8 + 0 + (kh >> 1)) * 256 + fo);
      p1 = (const u32*)(H2 + (tb2 + wv * 8 + 2 + (kh >> 1)) * 256 + fo);
      p2 = (const u32*)(H2 + (tb2 + wv * 8 + 4 + (kh >> 1)) * 256 + fo);
      p3 = (const u32*)(H2 + (tb2 + wv * 8 + 6 + (kh >> 1)) * 256 + fo);
      asm volatile(
          "global_load_dwordx4 %0, %4, off sc0 sc1\n\t"
          "global_load_dwordx4 %1, %5, off sc0 sc1\n\t"
          "global_load_dwordx4 %2, %6, off sc0 sc1\n\t"
          "global_load_dwordx4 %3, %7, off sc0 sc1"
          : "=&v"(q0), "=&v"(q1), "=&v"(q2), "=&v"(q3)
          : "v"(p0), "v"(p1), "v"(p2), "v"(p3)
          : "memory");
    }
    buf ^= 1;
  }
}

// ---------------------------------------------------------------------------
// em[t*64+b][tag] = [hf|hb] @ W_out^T + b_out. One block per t; blocked-H2 A.
__global__ __launch_bounds__(256) void k_emproj(
    const u16* __restrict__ H2, const float* __restrict__ Wo,
    const float* __restrict__ bo, float* __restrict__ em) {
  __shared__ u16 Wl[32 * 1024];
  const int tid = threadIdx.x, mb = blockIdx.x;
  const int wv = tid >> 6, lane = tid & 63, lm = lane & 15, kh = lane >> 4;
#pragma unroll
  for (int i = 0; i < 32; ++i) {        // stage Wo 32x1024 f32 -> bf16, rotated
    const int row = i, k = tid * 4;
    const float4 f = *(const float4*)(Wo + (size_t)row * 1024 + k);
    ushort4 s; s.x = f2b(f.x); s.y = f2b(f.y); s.z = f2b(f.z); s.w = f2b(f.w);
    *(ushort4*)&Wl[row * 1024 + ((k + 8 * row) & 1023)] = s;
  }
  __syncthreads();
  const f32x4 z = {0.f, 0.f, 0.f, 0.f};
  f32x4 acc[2] = {z, z};
#pragma unroll 2
  for (int kt = 0; kt < 32; ++kt) {     // k-global = kt*32 + kh*8 + j
    const int dd = kt >> 4;
    const int sG = (kt & 15) * 2 + (kh >> 1);
    const u16* ap = H2 + ((((size_t)mb * 2 + dd) * 4 + wv) * 32 + sG) * 256 + lm * 16 + (kh & 1) * 8;
    const bf16x8 a = *(const bf16x8*)ap;
#pragma unroll
    for (int ni = 0; ni < 2; ++ni) {
      const int row = ni * 16 + lm;
      const bf16x8 b = *(const bf16x8*)&Wl[row * 1024 + ((kt * 32 + kh * 8 + 8 * row) & 1023)];
      acc[ni] = __builtin_amdgcn_mfma_f32_16x16x32_bf16(a, b, acc[ni], 0, 0, 0);
    }
  }
#pragma unroll
  for (int ni = 0; ni < 2; ++ni) {
    const int n = ni * 16 + lm;
    const float bv = bo[n];
#pragma unroll
    for (int rr = 0; rr < 4; ++rr) {
      const int m = mb * 64 + wv * 16 + kh * 4 + rr;
      em[(size_t)m * 32 + n] = acc[ni][rr] + bv;
    }
  }
}

// ---------------------------------------------------------------------------
// CRF forward scans, fp32. One wave per (b, which). Register-resident: trans
// rows in 16 regs, alpha propagated via __shfl (no LDS, no barriers),
// possible-tag mask as __ballot bitmask, em/tgt 4-step prefetch pipeline.
// Same summation order as the LDS version => identical numerics.
__global__ __launch_bounds__(64) void k_crf(
    const float* __restrict__ em, const int* __restrict__ tgt,
    const float* __restrict__ trans, const float* __restrict__ stt,
    const float* __restrict__ ent, float* __restrict__ out) {
  const int lane = threadIdx.x;
  const int b = blockIdx.x >> 1;
  const int isnum = blockIdx.x & 1;
  const int k = lane & 31, j0 = (lane >> 5) * 16;
  float tr[16];
#pragma unroll
  for (int j = 0; j < 16; ++j) tr[j] = trans[(j0 + j) * 32 + k];

  float an; int nxt;
  {
    float a0 = stt[k] + em[(size_t)b * 32 + k];
    int p0 = 1;
    if (isnum) { p0 = tgt[((size_t)b * 512) * 32 + k]; if (p0 == 0) a0 = IMPOSSIBLE; }
    an = a0; nxt = p0;
  }
  u32 cmask = (u32)__ballot(nxt != 0);

  const size_t eb = (size_t)b * 32 + k;        // + t*2048
  const size_t tb = (size_t)b * 16384 + k;     // + t*32
  float e1 = em[eb + 1 * 2048], e2 = em[eb + 2 * 2048];
  float e3 = em[eb + 3 * 2048], e4 = em[eb + 4 * 2048];
  int g1 = 1, g2 = 1, g3 = 1, g4 = 1;
  if (isnum) {
    g1 = tgt[tb + 1 * 32]; g2 = tgt[tb + 2 * 32];
    g3 = tgt[tb + 3 * 32]; g4 = tgt[tb + 4 * 32];
  }

  auto step = [&](float e_raw, int nx) {
    const u32 cm = cmask >> j0;
    float vv[16];
#pragma unroll
    for (int j = 0; j < 16; ++j) {
      const float a = __shfl(an, j0 + j);            // alpha[j0+j], prev step
      float t_ = tr[j];
      if (isnum && ((((cm >> j) & 1u) == 0u) || nx == 0)) t_ = IMPOSSIBLE;
      vv[j] = a + t_;
    }
    const float m0 = fmaxf(fmaxf(fmaxf(vv[0], vv[1]), fmaxf(vv[2], vv[3])),
                           fmaxf(fmaxf(vv[4], vv[5]), fmaxf(vv[6], vv[7])));
    const float m1 = fmaxf(fmaxf(fmaxf(vv[8], vv[9]), fmaxf(vv[10], vv[11])),
                           fmaxf(fmaxf(vv[12], vv[13]), fmaxf(vv[14], vv[15])));
    const float m = fmaxf(m0, m1);                   // fmax tree: exact
    float ss = 0.f;
#pragma unroll
    for (int j = 0; j < 16; ++j) ss += __expf(vv[j] - m);   // same order as R7
    const float m2 = __shfl_xor(m, 32);
    const float s2 = __shfl_xor(ss, 32);
    const float M = fmaxf(m, m2);
    const float S = ss * __expf(m - M) + s2 * __expf(m2 - M);
    const float e = (isnum && nx == 0) ? IMPOSSIBLE : e_raw;
    an = M + __logf(S) + e;
    nxt = nx;
    if (isnum) cmask = (u32)__ballot(nx != 0);
  };

#pragma unroll 1
  for (int t = 1; t <= 505; t += 4) {                // steps t..t+3
    const int t7 = (t + 7 < 512) ? (t + 7) : 511;    // clamp last prefetch
    const float n1 = em[eb + (size_t)(t + 4) * 2048];
    const float n2 = em[eb + (size_t)(t + 5) * 2048];
    const float n3 = em[eb + (size_t)(t + 6) * 2048];
    const float n4 = em[eb + (size_t)t7 * 2048];
    int h1 = 1, h2 = 1, h3 = 1, h4 = 1;
    if (isnum) {
      h1 = tgt[tb + (size_t)(t + 4) * 32]; h2 = tgt[tb + (size_t)(t + 5) * 32];
      h3 = tgt[tb + (size_t)(t + 6) * 32]; h4 = tgt[tb + (size_t)t7 * 32];
    }
    step(e1, g1); step(e2, g2); step(e3, g3); step(e4, g4);
    e1 = n1; e2 = n2; e3 = n3; e4 = n4;
    g1 = h1; g2 = h2; g3 = h3; g4 = h4;
  }
  step(e1, g1); step(e2, g2); step(e3, g3);          // t = 509, 510, 511

  float x;
  if (!isnum) {
    x = an + ent[k];
  } else {
    const float et = ent[k] * (float)nxt;
    x = an + ((et == 0.f) ? IMPOSSIBLE : et);
  }
  float m = x;
#pragma unroll
  for (int o = 1; o < 32; o <<= 1) m = fmaxf(m, __shfl_xor(m, o));
  float ss = __expf(x - m);
#pragma unroll
  for (int o = 1; o < 32; o <<= 1) ss += __shfl_xor(ss, o);
  if (lane == 0) {
    const float rr = m + __logf(ss);
    atomicAdd(out, isnum ? -rr : rr);
  }
}

// ---------------------------------------------------------------------------
extern "C" void kernel_launch(void* const* d_in, const int* in_sizes, int n_in,
                              void* d_out, int out_size, void* d_ws, size_t ws_size,
                              hipStream_t stream) {
  (void)in_sizes; (void)n_in; (void)out_size; (void)ws_size;
  const int* sents = (const int*)d_in[0];
  const int* tgt = (const int*)d_in[2];
  const float* emb = (const float*)d_in[3];
  const float* Wif = (const float*)d_in[4];
  const float* Whf = (const float*)d_in[5];
  const float* bf_ = (const float*)d_in[6];
  const float* Wib = (const float*)d_in[7];
  const float* Whb = (const float*)d_in[8];
  const float* bb_ = (const float*)d_in[9];
  const float* Wo = (const float*)d_in[10];
  const float* bo = (const float*)d_in[11];
  const float* stt = (const float*)d_in[12];
  const float* ent = (const float*)d_in[13];
  const float* trans = (const float*)d_in[14];
  float* out = (float*)d_out;

  char* ws = (char*)d_ws;
  u16* x2 = (u16*)ws;                          // 16777216 B
  u16* H2 = (u16*)(ws + 16777216ull);          // 67108864 B (blocked)
  float* em = (float*)(ws + 83886080ull);      //  4194304 B

  k_init<<<dim3(16384), dim3(256), 0, stream>>>((u32*)H2, out);
  k_embed<<<dim3(512), dim3(256), 0, stream>>>(sents, emb, x2);
  k_lstm<<<dim3(256), dim3(256), 0, stream>>>(Whf, Whb, Wif, Wib, bf_, bb_, x2, H2);
  k_emproj<<<dim3(512), dim3(256), 0, stream>>>(H2, Wo, bo, em);
  k_crf<<<dim3(128), dim3(64), 0, stream>>>(em, tgt, trans, stt, ent, out);
}

// Round 6
// 1891.256 us; speedup vs baseline: 1.0265x; 1.0265x over previous
//
#include <hip/hip_runtime.h>

// BiLSTM + partial-CRF loss, MI355X (gfx950).
// R13: R12 post-mortem: early-issue polls sampled peers' lines BEFORE their
// stores committed -> read the canary line, which is MALL-cold -> HBM fetch
// (+31MB FETCH, ~900cy) on most first polls + retry RT. Early-issue is dead;
// R11's head-issue timing (sample ~ commit+eps) was near-optimal.
// R13 keeps R11's proven poll protocol and timing, and removes the OTHER
// serial cost: __syncthreads() emits s_waitcnt vmcnt(0) before s_barrier,
// which drained the previous h-store's MALL ack (~RT/2) every step. The
// canary protocol never needs that drain (consumers poll until visible), so
// the step's ONE barrier is now raw: asm lgkmcnt(0) -> s_barrier ->
// sched_barrier(0). LDS RAW across waves stays correct (each wave drains its
// own ds_writes); h-store + x-prefetch stay in flight across the barrier.
// Also kept from R12: double-buffered pre4 (WAR-safe at 2-barrier distance),
// x-fragment prefetch in the tail. k_init fused into k_embed (one dispatch).
// k_crf: R8's register-resident rewrite (validated, absmax 0).
//
// Sizes: B=64, L=512, V=50000, E=256, H=512, T=32.
// Workspace (~84 MiB):
//   x2   bf16 [512*64][256]                16777216 B @ 0
//   H2   bf16 blocked [t][d][g][s][256]    67108864 B @ 16777216
//   em   f32  [512*64][32]                  4194304 B @ 83886080

#define IMPOSSIBLE -10000.0f
#define CANARY 0x7FFF7FFFu

typedef __attribute__((ext_vector_type(8))) short bf16x8;
typedef __attribute__((ext_vector_type(4))) float f32x4;
typedef __attribute__((ext_vector_type(4))) unsigned int u32x4;
typedef unsigned int u32;
typedef unsigned short u16;

__device__ __forceinline__ u16 f2b(float f) {           // fp32 -> bf16 (RNE)
  union { float f; u32 u; } v; v.f = f;
  return (u16)((v.u + 0x7fffu + ((v.u >> 16) & 1u)) >> 16);
}
__device__ __forceinline__ float sigm(float x) { return 1.0f / (1.0f + __expf(-x)); }
__device__ __forceinline__ float tanh_f(float x) { return 1.0f - 2.0f / (__expf(2.0f * x) + 1.0f); }

__device__ __forceinline__ u32 can4(const u32x4& q) {
  return (u32)(q[0] == CANARY) | (u32)(q[1] == CANARY) |
         (u32)(q[2] == CANARY) | (u32)(q[3] == CANARY);
}

// ---------------------------------------------------------------------------
// Fused prep: blocks [0,16384) canary-fill H2 (plain dwordx4; dispatch-end
// flush publishes to MALL -- R11-proven) + out=0. Blocks [16384,16896):
// x2[t*64+b][e] = bf16(emb[sents[b][t]][e]), one block per t.
__global__ __launch_bounds__(256) void k_prep(
    const int* __restrict__ sents, const float* __restrict__ emb,
    u16* __restrict__ x2, u32* __restrict__ H2w, float* __restrict__ out) {
  const int bid = blockIdx.x, tid = threadIdx.x;
  if (bid < 16384) {
    const size_t i = ((size_t)bid * 256 + tid) * 4;
    const uint4 c4 = {CANARY, CANARY, CANARY, CANARY};
    *(uint4*)(H2w + i) = c4;
    if (bid == 0 && tid == 0)
      __hip_atomic_store((u32*)out, 0u, __ATOMIC_RELAXED, __HIP_MEMORY_SCOPE_AGENT);
    return;
  }
  const int t = bid - 16384;
  __shared__ int tok[64];
  if (tid < 64) tok[tid] = sents[tid * 512 + t];
  __syncthreads();
#pragma unroll
  for (int i = 0; i < 16; ++i) {
    const int v = i * 256 + tid;          // float4 index
    const int row = v >> 6, ke = (v & 63) * 4;
    const float4 f = *(const float4*)(emb + (size_t)tok[row] * 256 + ke);
    ushort4 s; s.x = f2b(f.x); s.y = f2b(f.y); s.z = f2b(f.z); s.w = f2b(f.w);
    *(ushort4*)&x2[((size_t)t * 64 + row) * 256 + ke] = s;
  }
}

// ---------------------------------------------------------------------------
// Persistent BiLSTM. 256 wgs x 256 thr, 1 wg/CU. group r=wid&7 -> (d=r>>2,
// g=r&3); slice s=wid>>3 (j0=s*16). Wave wv owns K-quarter for ALL 4 gates.
// Per step: issue poll burst (R11 timing) -> x MFMAs overlap flight -> tied
// vmcnt(0) + canary check + serial retry -> h MFMAs -> ds_write pre4[buf] ->
// RAW barrier WITHOUT vmcnt drain (lgkmcnt(0) + s_barrier + sched_barrier)
// -> x prefetch for it+1 -> reduce + gates -> packed agent h store.
__global__ __launch_bounds__(256, 1) void k_lstm(
    const float* __restrict__ Whf, const float* __restrict__ Whb,
    const float* __restrict__ Wif, const float* __restrict__ Wib,
    const float* __restrict__ bf_, const float* __restrict__ bb_,
    const u16* __restrict__ x2, u16* __restrict__ H2) {
  __shared__ float pre4[2][4096];       // double-buffered [wv][gate][kh][lm][rr]
  const int tid = threadIdx.x, wid = blockIdx.x;
  const int r = wid & 7, d = r >> 2, g = r & 3, s = wid >> 3;
  const int b0 = g * 16, j0 = s * 16;
  const float* __restrict__ Whh = d ? Whb : Whf;
  const float* __restrict__ Wih = d ? Wib : Wif;
  const float* __restrict__ bias = d ? bb_ : bf_;
  const int wv = tid >> 6, lane = tid & 63, lm = lane & 15, kh = lane >> 4;
  const int bl = tid >> 4, jj = tid & 15;

  // ---- weight fragments: B[k][n], n=lane&15, k = kh*8+j + 32*kt + wv*Kq ----
  bf16x8 wih_f[8], whh_f[16];
#pragma unroll
  for (int gg = 0; gg < 4; ++gg) {
    const float* wp = Wih + (size_t)(gg * 512 + j0 + lm) * 256 + wv * 64;
#pragma unroll
    for (int kt = 0; kt < 2; ++kt) {
      bf16x8 f;
#pragma unroll
      for (int j = 0; j < 8; ++j) f[j] = (short)f2b(wp[kt * 32 + kh * 8 + j]);
      wih_f[gg * 2 + kt] = f;
    }
    const float* wq = Whh + (size_t)(gg * 512 + j0 + lm) * 512 + wv * 128;
#pragma unroll
    for (int kt = 0; kt < 4; ++kt) {
      bf16x8 f;
#pragma unroll
      for (int j = 0; j < 8; ++j) f[j] = (short)f2b(wq[kt * 32 + kh * 8 + j]);
      whh_f[gg * 4 + kt] = f;
    }
  }
  const float b_i = bias[0 * 512 + j0 + jj];
  const float b_f = bias[1 * 512 + j0 + jj];
  const float b_g = bias[2 * 512 + j0 + jj];
  const float b_o = bias[3 * 512 + j0 + jj];

  float c = 0.f;
  const f32x4 z = {0.f, 0.f, 0.f, 0.f};
  int buf = 0;

  // prologue: x fragments for it=0
  bf16x8 xc0, xc1;
  {
    const int tt0 = d ? 511 : 0;
    const u16* xp = x2 + ((size_t)tt0 * 64 + b0 + lm) * 256 + wv * 64 + kh * 8;
    xc0 = *(const bf16x8*)xp;
    xc1 = *(const bf16x8*)(xp + 32);
  }

#pragma unroll 1
  for (int it = 0; it < 512; ++it) {
    const int tt = d ? (511 - it) : it;
    u32x4 q0, q1, q2, q3;
    const u32 *p0 = nullptr, *p1 = nullptr, *p2 = nullptr, *p3 = nullptr;
    if (it > 0) {
      // R11 timing: issue the poll burst at the HEAD (sample ~ commit + eps)
      const int tp = d ? (tt + 1) : (tt - 1);
      const size_t tb2 = (((size_t)tp * 2 + d) * 4 + g) * 32;
      const int fo = lm * 16 + (kh & 1) * 8;
      p0 = (const u32*)(H2 + (tb2 + wv * 8 + 0 + (kh >> 1)) * 256 + fo);
      p1 = (const u32*)(H2 + (tb2 + wv * 8 + 2 + (kh >> 1)) * 256 + fo);
      p2 = (const u32*)(H2 + (tb2 + wv * 8 + 4 + (kh >> 1)) * 256 + fo);
      p3 = (const u32*)(H2 + (tb2 + wv * 8 + 6 + (kh >> 1)) * 256 + fo);
      asm volatile(
          "global_load_dwordx4 %0, %4, off sc0 sc1\n\t"
          "global_load_dwordx4 %1, %5, off sc0 sc1\n\t"
          "global_load_dwordx4 %2, %6, off sc0 sc1\n\t"
          "global_load_dwordx4 %3, %7, off sc0 sc1"
          : "=&v"(q0), "=&v"(q1), "=&v"(q2), "=&v"(q3)
          : "v"(p0), "v"(p1), "v"(p2), "v"(p3)
          : "memory");
    }
    f32x4 accg[4] = {z, z, z, z};
    // x MFMAs fill the poll flight time
#pragma unroll
    for (int gg = 0; gg < 4; ++gg) {
      accg[gg] = __builtin_amdgcn_mfma_f32_16x16x32_bf16(xc0, wih_f[gg * 2 + 0], accg[gg], 0, 0, 0);
      accg[gg] = __builtin_amdgcn_mfma_f32_16x16x32_bf16(xc1, wih_f[gg * 2 + 1], accg[gg], 0, 0, 0);
    }
    if (it > 0) {
      // tied wait: q regs flow through the asm -> check can't hoist above it
      asm volatile("s_waitcnt vmcnt(0)"
                   : "+v"(q0), "+v"(q1), "+v"(q2), "+v"(q3) :: "memory");
      u32 anybad = can4(q0) | can4(q1) | can4(q2) | can4(q3);
      int bud = 4096;       // on exhaust: canary NaNs propagate -> absmax fail
      while (__any(anybad != 0) && --bud) {
        asm volatile(
            "global_load_dwordx4 %0, %4, off sc0 sc1\n\t"
            "global_load_dwordx4 %1, %5, off sc0 sc1\n\t"
            "global_load_dwordx4 %2, %6, off sc0 sc1\n\t"
            "global_load_dwordx4 %3, %7, off sc0 sc1\n\t"
            "s_waitcnt vmcnt(0)"
            : "=&v"(q0), "=&v"(q1), "=&v"(q2), "=&v"(q3)
            : "v"(p0), "v"(p1), "v"(p2), "v"(p3)
            : "memory");
        anybad = can4(q0) | can4(q1) | can4(q2) | can4(q3);
      }
      union { u32x4 q; bf16x8 v; } c0, c1, c2, c3;
      c0.q = q0; c1.q = q1; c2.q = q2; c3.q = q3;
#pragma unroll
      for (int gg = 0; gg < 4; ++gg) {
        accg[gg] = __builtin_amdgcn_mfma_f32_16x16x32_bf16(c0.v, whh_f[gg * 4 + 0], accg[gg], 0, 0, 0);
        accg[gg] = __builtin_amdgcn_mfma_f32_16x16x32_bf16(c1.v, whh_f[gg * 4 + 1], accg[gg], 0, 0, 0);
        accg[gg] = __builtin_amdgcn_mfma_f32_16x16x32_bf16(c2.v, whh_f[gg * 4 + 2], accg[gg], 0, 0, 0);
        accg[gg] = __builtin_amdgcn_mfma_f32_16x16x32_bf16(c3.v, whh_f[gg * 4 + 3], accg[gg], 0, 0, 0);
      }
    }
    // partials -> LDS buf, one ds_write_b128 per gate
#pragma unroll
    for (int gg = 0; gg < 4; ++gg)
      *(f32x4*)&pre4[buf][wv * 1024 + gg * 256 + kh * 64 + lm * 4] = accg[gg];
    // RAW barrier WITHOUT the implicit vmcnt(0) drain: the h store and any
    // in-flight loads stay outstanding across it (canary protocol needs no
    // store drain). Own ds_writes drained via lgkmcnt(0); sched_barrier
    // fences reordering around the inline-asm wait (rule #18).
    asm volatile("s_waitcnt lgkmcnt(0)" ::: "memory");
    __builtin_amdgcn_s_barrier();
    __builtin_amdgcn_sched_barrier(0);
    if (it < 511) {         // prefetch x for it+1; lands during tail + next head
      const int ttn = d ? (tt - 1) : (tt + 1);
      const u16* xp = x2 + ((size_t)ttn * 64 + b0 + lm) * 256 + wv * 64 + kh * 8;
      xc0 = *(const bf16x8*)xp;
      xc1 = *(const bf16x8*)(xp + 32);
    }
    const int off = (bl >> 2) * 64 + jj * 4 + (bl & 3);
    float pi = b_i, pf = b_f, pg = b_g, po = b_o;
#pragma unroll
    for (int w4 = 0; w4 < 4; ++w4) {
      pi += pre4[buf][w4 * 1024 + 0   + off];
      pf += pre4[buf][w4 * 1024 + 256 + off];
      pg += pre4[buf][w4 * 1024 + 512 + off];
      po += pre4[buf][w4 * 1024 + 768 + off];
    }
    c = sigm(pf) * c + sigm(pi) * tanh_f(pg);
    const float h = sigm(po) * tanh_f(c);
    const float hq = __shfl_xor(h, 1);
    if ((tid & 1) == 0) {   // block element = tid; pack pair -> u32, agent store
      const u32 pk = (u32)f2b(h) | ((u32)f2b(hq) << 16);
      u32* hp2 = (u32*)H2 + ((((size_t)tt * 2 + d) * 4 + g) * 32 + s) * 128 + (tid >> 1);
      __hip_atomic_store(hp2, pk, __ATOMIC_RELAXED, __HIP_MEMORY_SCOPE_AGENT);
    }
    // no drain, no flag: consumers poll the data dwords themselves
    buf ^= 1;
  }
}

// ---------------------------------------------------------------------------
// em[t*64+b][tag] = [hf|hb] @ W_out^T + b_out. One block per t; blocked-H2 A.
__global__ __launch_bounds__(256) void k_emproj(
    const u16* __restrict__ H2, const float* __restrict__ Wo,
    const float* __restrict__ bo, float* __restrict__ em) {
  __shared__ u16 Wl[32 * 1024];
  const int tid = threadIdx.x, mb = blockIdx.x;
  const int wv = tid >> 6, lane = tid & 63, lm = lane & 15, kh = lane >> 4;
#pragma unroll
  for (int i = 0; i < 32; ++i) {        // stage Wo 32x1024 f32 -> bf16, rotated
    const int row = i, k = tid * 4;
    const float4 f = *(const float4*)(Wo + (size_t)row * 1024 + k);
    ushort4 s; s.x = f2b(f.x); s.y = f2b(f.y); s.z = f2b(f.z); s.w = f2b(f.w);
    *(ushort4*)&Wl[row * 1024 + ((k + 8 * row) & 1023)] = s;
  }
  __syncthreads();
  const f32x4 z = {0.f, 0.f, 0.f, 0.f};
  f32x4 acc[2] = {z, z};
#pragma unroll 2
  for (int kt = 0; kt < 32; ++kt) {     // k-global = kt*32 + kh*8 + j
    const int dd = kt >> 4;
    const int sG = (kt & 15) * 2 + (kh >> 1);
    const u16* ap = H2 + ((((size_t)mb * 2 + dd) * 4 + wv) * 32 + sG) * 256 + lm * 16 + (kh & 1) * 8;
    const bf16x8 a = *(const bf16x8*)ap;
#pragma unroll
    for (int ni = 0; ni < 2; ++ni) {
      const int row = ni * 16 + lm;
      const bf16x8 b = *(const bf16x8*)&Wl[row * 1024 + ((kt * 32 + kh * 8 + 8 * row) & 1023)];
      acc[ni] = __builtin_amdgcn_mfma_f32_16x16x32_bf16(a, b, acc[ni], 0, 0, 0);
    }
  }
#pragma unroll
  for (int ni = 0; ni < 2; ++ni) {
    const int n = ni * 16 + lm;
    const float bv = bo[n];
#pragma unroll
    for (int rr = 0; rr < 4; ++rr) {
      const int m = mb * 64 + wv * 16 + kh * 4 + rr;
      em[(size_t)m * 32 + n] = acc[ni][rr] + bv;
    }
  }
}

// ---------------------------------------------------------------------------
// CRF forward scans, fp32. One wave per (b, which). Register-resident: trans
// rows in 16 regs, alpha propagated via __shfl (no LDS, no barriers),
// possible-tag mask as __ballot bitmask, em/tgt 4-step prefetch pipeline.
// Same summation order as the LDS version => identical numerics.
__global__ __launch_bounds__(64) void k_crf(
    const float* __restrict__ em, const int* __restrict__ tgt,
    const float* __restrict__ trans, const float* __restrict__ stt,
    const float* __restrict__ ent, float* __restrict__ out) {
  const int lane = threadIdx.x;
  const int b = blockIdx.x >> 1;
  const int isnum = blockIdx.x & 1;
  const int k = lane & 31, j0 = (lane >> 5) * 16;
  float tr[16];
#pragma unroll
  for (int j = 0; j < 16; ++j) tr[j] = trans[(j0 + j) * 32 + k];

  float an; int nxt;
  {
    float a0 = stt[k] + em[(size_t)b * 32 + k];
    int p0 = 1;
    if (isnum) { p0 = tgt[((size_t)b * 512) * 32 + k]; if (p0 == 0) a0 = IMPOSSIBLE; }
    an = a0; nxt = p0;
  }
  u32 cmask = (u32)__ballot(nxt != 0);

  const size_t eb = (size_t)b * 32 + k;        // + t*2048
  const size_t tb = (size_t)b * 16384 + k;     // + t*32
  float e1 = em[eb + 1 * 2048], e2 = em[eb + 2 * 2048];
  float e3 = em[eb + 3 * 2048], e4 = em[eb + 4 * 2048];
  int g1 = 1, g2 = 1, g3 = 1, g4 = 1;
  if (isnum) {
    g1 = tgt[tb + 1 * 32]; g2 = tgt[tb + 2 * 32];
    g3 = tgt[tb + 3 * 32]; g4 = tgt[tb + 4 * 32];
  }

  auto step = [&](float e_raw, int nx) {
    const u32 cm = cmask >> j0;
    float vv[16];
#pragma unroll
    for (int j = 0; j < 16; ++j) {
      const float a = __shfl(an, j0 + j);            // alpha[j0+j], prev step
      float t_ = tr[j];
      if (isnum && ((((cm >> j) & 1u) == 0u) || nx == 0)) t_ = IMPOSSIBLE;
      vv[j] = a + t_;
    }
    const float m0 = fmaxf(fmaxf(fmaxf(vv[0], vv[1]), fmaxf(vv[2], vv[3])),
                           fmaxf(fmaxf(vv[4], vv[5]), fmaxf(vv[6], vv[7])));
    const float m1 = fmaxf(fmaxf(fmaxf(vv[8], vv[9]), fmaxf(vv[10], vv[11])),
                           fmaxf(fmaxf(vv[12], vv[13]), fmaxf(vv[14], vv[15])));
    const float m = fmaxf(m0, m1);                   // fmax tree: exact
    float ss = 0.f;
#pragma unroll
    for (int j = 0; j < 16; ++j) ss += __expf(vv[j] - m);   // same order as R7
    const float m2 = __shfl_xor(m, 32);
    const float s2 = __shfl_xor(ss, 32);
    const float M = fmaxf(m, m2);
    const float S = ss * __expf(m - M) + s2 * __expf(m2 - M);
    const float e = (isnum && nx == 0) ? IMPOSSIBLE : e_raw;
    an = M + __logf(S) + e;
    nxt = nx;
    if (isnum) cmask = (u32)__ballot(nx != 0);
  };

#pragma unroll 1
  for (int t = 1; t <= 505; t += 4) {                // steps t..t+3
    const int t7 = (t + 7 < 512) ? (t + 7) : 511;    // clamp last prefetch
    const float n1 = em[eb + (size_t)(t + 4) * 2048];
    const float n2 = em[eb + (size_t)(t + 5) * 2048];
    const float n3 = em[eb + (size_t)(t + 6) * 2048];
    const float n4 = em[eb + (size_t)t7 * 2048];
    int h1 = 1, h2 = 1, h3 = 1, h4 = 1;
    if (isnum) {
      h1 = tgt[tb + (size_t)(t + 4) * 32]; h2 = tgt[tb + (size_t)(t + 5) * 32];
      h3 = tgt[tb + (size_t)(t + 6) * 32]; h4 = tgt[tb + (size_t)t7 * 32];
    }
    step(e1, g1); step(e2, g2); step(e3, g3); step(e4, g4);
    e1 = n1; e2 = n2; e3 = n3; e4 = n4;
    g1 = h1; g2 = h2; g3 = h3; g4 = h4;
  }
  step(e1, g1); step(e2, g2); step(e3, g3);          // t = 509, 510, 511

  float x;
  if (!isnum) {
    x = an + ent[k];
  } else {
    const float et = ent[k] * (float)nxt;
    x = an + ((et == 0.f) ? IMPOSSIBLE : et);
  }
  float m = x;
#pragma unroll
  for (int o = 1; o < 32; o <<= 1) m = fmaxf(m, __shfl_xor(m, o));
  float ss = __expf(x - m);
#pragma unroll
  for (int o = 1; o < 32; o <<= 1) ss += __shfl_xor(ss, o);
  if (lane == 0) {
    const float rr = m + __logf(ss);
    atomicAdd(out, isnum ? -rr : rr);
  }
}

// ---------------------------------------------------------------------------
extern "C" void kernel_launch(void* const* d_in, const int* in_sizes, int n_in,
                              void* d_out, int out_size, void* d_ws, size_t ws_size,
                              hipStream_t stream) {
  (void)in_sizes; (void)n_in; (void)out_size; (void)ws_size;
  const int* sents = (const int*)d_in[0];
  const int* tgt = (const int*)d_in[2];
  const float* emb = (const float*)d_in[3];
  const float* Wif = (const float*)d_in[4];
  const float* Whf = (const float*)d_in[5];
  const float* bf_ = (const float*)d_in[6];
  const float* Wib = (const float*)d_in[7];
  const float* Whb = (const float*)d_in[8];
  const float* bb_ = (const float*)d_in[9];
  const float* Wo = (const float*)d_in[10];
  const float* bo = (const float*)d_in[11];
  const float* stt = (const float*)d_in[12];
  const float* ent = (const float*)d_in[13];
  const float* trans = (const float*)d_in[14];
  float* out = (float*)d_out;

  char* ws = (char*)d_ws;
  u16* x2 = (u16*)ws;                          // 16777216 B
  u16* H2 = (u16*)(ws + 16777216ull);          // 67108864 B (blocked)
  float* em = (float*)(ws + 83886080ull);      //  4194304 B

  k_prep<<<dim3(16896), dim3(256), 0, stream>>>(sents, emb, x2, (u32*)H2, out);
  k_lstm<<<dim3(256), dim3(256), 0, stream>>>(Whf, Whb, Wif, Wib, bf_, bb_, x2, H2);
  k_emproj<<<dim3(512), dim3(256), 0, stream>>>(H2, Wo, bo, em);
  k_crf<<<dim3(128), dim3(64), 0, stream>>>(em, tgt, trans, stt, ent, out);
}

// Round 7
// 1657.340 us; speedup vs baseline: 1.1713x; 1.1411x over previous
//
#include <hip/hip_runtime.h>

// BiLSTM + partial-CRF loss, MI355X (gfx950).
// R14: R11-verbatim protocol (965us proven: 2 __syncthreads, single pre4,
// head-issued polls) + two additive fixes derived from R11's FETCH=92MB
// (~= x2 16MB + ALL of H2 67MB): the 67MB is the h-store RMW pulling each
// canary line from HBM (~900cy) before the store can commit at MALL -- that
// commit latency delays every peer's poll detect.
//  (1) PRE-WARM: at step head every thread issues a plain cached discard-
//      load of its own upcoming h-store address; the HBM line fetch happens
//      in the head window (overlapped with the already-HBM-cold x loads),
//      so the tail store commits into a MALL-resident line.
//  (2) PROBE-FIRST RETRY: 1 probe dword/lane issued (older in vmcnt order)
//      with the 4 data quads. Happy path = vmcnt(4) probe check then
//      vmcnt(0) data check (same latency as R11). Miss path re-polls only
//      256B/wave (16x less fabric traffic) until ready, then one data
//      reissue; R11's full retry loop kept as the final guard.
// R13 lesson kept: polls must never run earlier than R11's phase (premature
// polls read MALL-cold canary lines from HBM: +23MB FETCH, +400us).
// k_crf: R8's register-resident rewrite (validated). k_prep: fused fill.
//
// Sizes: B=64, L=512, V=50000, E=256, H=512, T=32.
// Workspace (~84 MiB):
//   x2   bf16 [512*64][256]                16777216 B @ 0
//   H2   bf16 blocked [t][d][g][s][256]    67108864 B @ 16777216
//   em   f32  [512*64][32]                  4194304 B @ 83886080

#define IMPOSSIBLE -10000.0f
#define CANARY 0x7FFF7FFFu

typedef __attribute__((ext_vector_type(8))) short bf16x8;
typedef __attribute__((ext_vector_type(4))) float f32x4;
typedef __attribute__((ext_vector_type(4))) unsigned int u32x4;
typedef unsigned int u32;
typedef unsigned short u16;

__device__ __forceinline__ u16 f2b(float f) {           // fp32 -> bf16 (RNE)
  union { float f; u32 u; } v; v.f = f;
  return (u16)((v.u + 0x7fffu + ((v.u >> 16) & 1u)) >> 16);
}
__device__ __forceinline__ float sigm(float x) { return 1.0f / (1.0f + __expf(-x)); }
__device__ __forceinline__ float tanh_f(float x) { return 1.0f - 2.0f / (__expf(2.0f * x) + 1.0f); }

__device__ __forceinline__ u32 can4(const u32x4& q) {
  return (u32)(q[0] == CANARY) | (u32)(q[1] == CANARY) |
         (u32)(q[2] == CANARY) | (u32)(q[3] == CANARY);
}

// ---------------------------------------------------------------------------
// Fused prep: blocks [0,16384) canary-fill H2 (plain dwordx4; dispatch-end
// flush publishes -- R11-proven) + out=0. Blocks [16384,16896): x2 embed.
__global__ __launch_bounds__(256) void k_prep(
    const int* __restrict__ sents, const float* __restrict__ emb,
    u16* __restrict__ x2, u32* __restrict__ H2w, float* __restrict__ out) {
  const int bid = blockIdx.x, tid = threadIdx.x;
  if (bid < 16384) {
    const size_t i = ((size_t)bid * 256 + tid) * 4;
    const uint4 c4 = {CANARY, CANARY, CANARY, CANARY};
    *(uint4*)(H2w + i) = c4;
    if (bid == 0 && tid == 0)
      __hip_atomic_store((u32*)out, 0u, __ATOMIC_RELAXED, __HIP_MEMORY_SCOPE_AGENT);
    return;
  }
  const int t = bid - 16384;
  __shared__ int tok[64];
  if (tid < 64) tok[tid] = sents[tid * 512 + t];
  __syncthreads();
#pragma unroll
  for (int i = 0; i < 16; ++i) {
    const int v = i * 256 + tid;          // float4 index
    const int row = v >> 6, ke = (v & 63) * 4;
    const float4 f = *(const float4*)(emb + (size_t)tok[row] * 256 + ke);
    ushort4 s; s.x = f2b(f.x); s.y = f2b(f.y); s.z = f2b(f.z); s.w = f2b(f.w);
    *(ushort4*)&x2[((size_t)t * 64 + row) * 256 + ke] = s;
  }
}

// ---------------------------------------------------------------------------
// Persistent BiLSTM. 256 wgs x 256 thr, 1 wg/CU. group r=wid&7 -> (d=r>>2,
// g=r&3); slice s=wid>>3 (j0=s*16). Wave wv owns K-quarter for ALL 4 gates.
// Per step (R11 order): one asm burst {x b128 x2, self-prewarm dword, probe
// dword, 4 data quads} -> vmcnt(6) x MFMAs -> vmcnt(4) probe check ->
// vmcnt(0) data check (+cheap probe loop / full retry on miss) -> h MFMAs ->
// sync -> ds_write pre4 -> sync -> reduce + gates -> packed agent h store.
__global__ __launch_bounds__(256, 1) void k_lstm(
    const float* __restrict__ Whf, const float* __restrict__ Whb,
    const float* __restrict__ Wif, const float* __restrict__ Wib,
    const float* __restrict__ bf_, const float* __restrict__ bb_,
    const u16* __restrict__ x2, u16* __restrict__ H2) {
  __shared__ float pre4[4096];          // [wv][gate][kh][lm][rr]
  const int tid = threadIdx.x, wid = blockIdx.x;
  const int r = wid & 7, d = r >> 2, g = r & 3, s = wid >> 3;
  const int b0 = g * 16, j0 = s * 16;
  const float* __restrict__ Whh = d ? Whb : Whf;
  const float* __restrict__ Wih = d ? Wib : Wif;
  const float* __restrict__ bias = d ? bb_ : bf_;
  const int wv = tid >> 6, lane = tid & 63, lm = lane & 15, kh = lane >> 4;
  const int bl = tid >> 4, jj = tid & 15;

  // ---- weight fragments: B[k][n], n=lane&15, k = kh*8+j + 32*kt + wv*Kq ----
  bf16x8 wih_f[8], whh_f[16];
#pragma unroll
  for (int gg = 0; gg < 4; ++gg) {
    const float* wp = Wih + (size_t)(gg * 512 + j0 + lm) * 256 + wv * 64;
#pragma unroll
    for (int kt = 0; kt < 2; ++kt) {
      bf16x8 f;
#pragma unroll
      for (int j = 0; j < 8; ++j) f[j] = (short)f2b(wp[kt * 32 + kh * 8 + j]);
      wih_f[gg * 2 + kt] = f;
    }
    const float* wq = Whh + (size_t)(gg * 512 + j0 + lm) * 512 + wv * 128;
#pragma unroll
    for (int kt = 0; kt < 4; ++kt) {
      bf16x8 f;
#pragma unroll
      for (int j = 0; j < 8; ++j) f[j] = (short)f2b(wq[kt * 32 + kh * 8 + j]);
      whh_f[gg * 4 + kt] = f;
    }
  }
  const float b_i = bias[0 * 512 + j0 + jj];
  const float b_f = bias[1 * 512 + j0 + jj];
  const float b_g = bias[2 * 512 + j0 + jj];
  const float b_o = bias[3 * 512 + j0 + jj];

  float c = 0.f;
  const f32x4 z = {0.f, 0.f, 0.f, 0.f};
#pragma unroll 1
  for (int it = 0; it < 512; ++it) {
    const int tt = d ? (511 - it) : it;
    const u16* xp = x2 + ((size_t)tt * 64 + b0 + lm) * 256 + wv * 64 + kh * 8;
    u32* hp2 = (u32*)H2 + ((((size_t)tt * 2 + d) * 4 + g) * 32 + s) * 128 + (tid >> 1);
    f32x4 accg[4] = {z, z, z, z};
    if (it > 0) {
      const int tp = d ? (tt + 1) : (tt - 1);
      const size_t tb2 = (((size_t)tp * 2 + d) * 4 + g) * 32;
      const int fo = lm * 16 + (kh & 1) * 8;
      const u32* p0 = (const u32*)(H2 + (tb2 + wv * 8 + 0 + (kh >> 1)) * 256 + fo);
      const u32* p1 = (const u32*)(H2 + (tb2 + wv * 8 + 2 + (kh >> 1)) * 256 + fo);
      const u32* p2 = (const u32*)(H2 + (tb2 + wv * 8 + 4 + (kh >> 1)) * 256 + fo);
      const u32* p3 = (const u32*)(H2 + (tb2 + wv * 8 + 6 + (kh >> 1)) * 256 + fo);
      // probe: lane l -> slice wv*8+(l&7), dword (l>>3) of the row
      const u32* pr = (const u32*)(H2 + (tb2 + wv * 8 + (lane & 7)) * 256) + (lane >> 3);
      u32x4 xu0, xu1, q0, q1, q2, q3;
      u32 pw, pv;
      // one burst, fixed vmcnt order: x,x (oldest), prewarm, probe, data x4
      asm volatile(
          "global_load_dwordx4 %0, %8, off\n\t"
          "global_load_dwordx4 %1, %9, off\n\t"
          "global_load_dword  %2, %10, off\n\t"
          "global_load_dword  %3, %11, off sc0 sc1\n\t"
          "global_load_dwordx4 %4, %12, off sc0 sc1\n\t"
          "global_load_dwordx4 %5, %13, off sc0 sc1\n\t"
          "global_load_dwordx4 %6, %14, off sc0 sc1\n\t"
          "global_load_dwordx4 %7, %15, off sc0 sc1"
          : "=&v"(xu0), "=&v"(xu1), "=&v"(pw), "=&v"(pv),
            "=&v"(q0), "=&v"(q1), "=&v"(q2), "=&v"(q3)
          : "v"(xp), "v"(xp + 32), "v"(hp2), "v"(pr),
            "v"(p0), "v"(p1), "v"(p2), "v"(p3)
          : "memory");
      asm volatile("s_waitcnt vmcnt(6)" : "+v"(xu0), "+v"(xu1) :: "memory");
      union { u32x4 q; bf16x8 v; } xc0, xc1;
      xc0.q = xu0; xc1.q = xu1;
#pragma unroll
      for (int gg = 0; gg < 4; ++gg) {
        accg[gg] = __builtin_amdgcn_mfma_f32_16x16x32_bf16(xc0.v, wih_f[gg * 2 + 0], accg[gg], 0, 0, 0);
        accg[gg] = __builtin_amdgcn_mfma_f32_16x16x32_bf16(xc1.v, wih_f[gg * 2 + 1], accg[gg], 0, 0, 0);
      }
      asm volatile("s_waitcnt vmcnt(4)" : "+v"(pv) :: "memory");
      const bool pbad = __any(pv == CANARY);
      asm volatile("s_waitcnt vmcnt(0)"
                   : "+v"(q0), "+v"(q1), "+v"(q2), "+v"(q3) :: "memory");
      if (pbad) {
        // cheap re-probe: 256B/wave per round (16x less than full reissue)
        int budp = 1 << 16;
        u32 pv2 = pv;
        while (__any(pv2 == CANARY) && --budp) {
          asm volatile(
              "global_load_dword %0, %1, off sc0 sc1\n\t"
              "s_waitcnt vmcnt(0)"
              : "=&v"(pv2) : "v"(pr) : "memory");
        }
        asm volatile(          // one data reissue now that probes pass
            "global_load_dwordx4 %0, %4, off sc0 sc1\n\t"
            "global_load_dwordx4 %1, %5, off sc0 sc1\n\t"
            "global_load_dwordx4 %2, %6, off sc0 sc1\n\t"
            "global_load_dwordx4 %3, %7, off sc0 sc1\n\t"
            "s_waitcnt vmcnt(0)"
            : "=&v"(q0), "=&v"(q1), "=&v"(q2), "=&v"(q3)
            : "v"(p0), "v"(p1), "v"(p2), "v"(p3)
            : "memory");
      }
      // full guard (R11-proven): on exhaust canary NaNs -> absmax fail
      u32 anybad = can4(q0) | can4(q1) | can4(q2) | can4(q3);
      int bud = 4096;
      while (__any(anybad != 0) && --bud) {
        asm volatile(
            "global_load_dwordx4 %0, %4, off sc0 sc1\n\t"
            "global_load_dwordx4 %1, %5, off sc0 sc1\n\t"
            "global_load_dwordx4 %2, %6, off sc0 sc1\n\t"
            "global_load_dwordx4 %3, %7, off sc0 sc1\n\t"
            "s_waitcnt vmcnt(0)"
            : "=&v"(q0), "=&v"(q1), "=&v"(q2), "=&v"(q3)
            : "v"(p0), "v"(p1), "v"(p2), "v"(p3)
            : "memory");
        anybad = can4(q0) | can4(q1) | can4(q2) | can4(q3);
      }
      union { u32x4 q; bf16x8 v; } c0, c1, c2, c3;
      c0.q = q0; c1.q = q1; c2.q = q2; c3.q = q3;
#pragma unroll
      for (int gg = 0; gg < 4; ++gg) {
        accg[gg] = __builtin_amdgcn_mfma_f32_16x16x32_bf16(c0.v, whh_f[gg * 4 + 0], accg[gg], 0, 0, 0);
        accg[gg] = __builtin_amdgcn_mfma_f32_16x16x32_bf16(c1.v, whh_f[gg * 4 + 1], accg[gg], 0, 0, 0);
        accg[gg] = __builtin_amdgcn_mfma_f32_16x16x32_bf16(c2.v, whh_f[gg * 4 + 2], accg[gg], 0, 0, 0);
        accg[gg] = __builtin_amdgcn_mfma_f32_16x16x32_bf16(c3.v, whh_f[gg * 4 + 3], accg[gg], 0, 0, 0);
      }
    } else {
      // it==0: plain x loads + self-prewarm only
      u32 pw;
      asm volatile("global_load_dword %0, %1, off"
                   : "=&v"(pw) : "v"(hp2) : "memory");
      const bf16x8 xa0 = *(const bf16x8*)xp;
      const bf16x8 xa1 = *(const bf16x8*)(xp + 32);
#pragma unroll
      for (int gg = 0; gg < 4; ++gg) {
        accg[gg] = __builtin_amdgcn_mfma_f32_16x16x32_bf16(xa0, wih_f[gg * 2 + 0], accg[gg], 0, 0, 0);
        accg[gg] = __builtin_amdgcn_mfma_f32_16x16x32_bf16(xa1, wih_f[gg * 2 + 1], accg[gg], 0, 0, 0);
      }
    }
    __syncthreads();        // WAR: prior step's pre4 reads complete
    // partials -> LDS, one ds_write_b128 per gate (layout [wv][g][kh][lm][rr])
#pragma unroll
    for (int gg = 0; gg < 4; ++gg)
      *(f32x4*)&pre4[wv * 1024 + gg * 256 + kh * 64 + lm * 4] = accg[gg];
    __syncthreads();        // RAW: partials visible
    const int off = (bl >> 2) * 64 + jj * 4 + (bl & 3);
    float pi = b_i, pf = b_f, pg = b_g, po = b_o;
#pragma unroll
    for (int w4 = 0; w4 < 4; ++w4) {
      pi += pre4[w4 * 1024 + 0   + off];
      pf += pre4[w4 * 1024 + 256 + off];
      pg += pre4[w4 * 1024 + 512 + off];
      po += pre4[w4 * 1024 + 768 + off];
    }
    c = sigm(pf) * c + sigm(pi) * tanh_f(pg);
    const float h = sigm(po) * tanh_f(c);
    const float hq = __shfl_xor(h, 1);
    if ((tid & 1) == 0) {   // block element = tid; pack pair -> u32, agent store
      const u32 pk = (u32)f2b(h) | ((u32)f2b(hq) << 16);
      __hip_atomic_store(hp2, pk, __ATOMIC_RELAXED, __HIP_MEMORY_SCOPE_AGENT);
    }
    // no drain, no flag: consumers poll the data dwords themselves
  }
}

// ---------------------------------------------------------------------------
// em[t*64+b][tag] = [hf|hb] @ W_out^T + b_out. One block per t; blocked-H2 A.
__global__ __launch_bounds__(256) void k_emproj(
    const u16* __restrict__ H2, const float* __restrict__ Wo,
    const float* __restrict__ bo, float* __restrict__ em) {
  __shared__ u16 Wl[32 * 1024];
  const int tid = threadIdx.x, mb = blockIdx.x;
  const int wv = tid >> 6, lane = tid & 63, lm = lane & 15, kh = lane >> 4;
#pragma unroll
  for (int i = 0; i < 32; ++i) {        // stage Wo 32x1024 f32 -> bf16, rotated
    const int row = i, k = tid * 4;
    const float4 f = *(const float4*)(Wo + (size_t)row * 1024 + k);
    ushort4 s; s.x = f2b(f.x); s.y = f2b(f.y); s.z = f2b(f.z); s.w = f2b(f.w);
    *(ushort4*)&Wl[row * 1024 + ((k + 8 * row) & 1023)] = s;
  }
  __syncthreads();
  const f32x4 z = {0.f, 0.f, 0.f, 0.f};
  f32x4 acc[2] = {z, z};
#pragma unroll 2
  for (int kt = 0; kt < 32; ++kt) {     // k-global = kt*32 + kh*8 + j
    const int dd = kt >> 4;
    const int sG = (kt & 15) * 2 + (kh >> 1);
    const u16* ap = H2 + ((((size_t)mb * 2 + dd) * 4 + wv) * 32 + sG) * 256 + lm * 16 + (kh & 1) * 8;
    const bf16x8 a = *(const bf16x8*)ap;
#pragma unroll
    for (int ni = 0; ni < 2; ++ni) {
      const int row = ni * 16 + lm;
      const bf16x8 b = *(const bf16x8*)&Wl[row * 1024 + ((kt * 32 + kh * 8 + 8 * row) & 1023)];
      acc[ni] = __builtin_amdgcn_mfma_f32_16x16x32_bf16(a, b, acc[ni], 0, 0, 0);
    }
  }
#pragma unroll
  for (int ni = 0; ni < 2; ++ni) {
    const int n = ni * 16 + lm;
    const float bv = bo[n];
#pragma unroll
    for (int rr = 0; rr < 4; ++rr) {
      const int m = mb * 64 + wv * 16 + kh * 4 + rr;
      em[(size_t)m * 32 + n] = acc[ni][rr] + bv;
    }
  }
}

// ---------------------------------------------------------------------------
// CRF forward scans, fp32. One wave per (b, which). Register-resident: trans
// rows in 16 regs, alpha propagated via __shfl (no LDS, no barriers),
// possible-tag mask as __ballot bitmask, em/tgt 4-step prefetch pipeline.
// Same summation order as the LDS version => identical numerics.
__global__ __launch_bounds__(64) void k_crf(
    const float* __restrict__ em, const int* __restrict__ tgt,
    const float* __restrict__ trans, const float* __restrict__ stt,
    const float* __restrict__ ent, float* __restrict__ out) {
  const int lane = threadIdx.x;
  const int b = blockIdx.x >> 1;
  const int isnum = blockIdx.x & 1;
  const int k = lane & 31, j0 = (lane >> 5) * 16;
  float tr[16];
#pragma unroll
  for (int j = 0; j < 16; ++j) tr[j] = trans[(j0 + j) * 32 + k];

  float an; int nxt;
  {
    float a0 = stt[k] + em[(size_t)b * 32 + k];
    int p0 = 1;
    if (isnum) { p0 = tgt[((size_t)b * 512) * 32 + k]; if (p0 == 0) a0 = IMPOSSIBLE; }
    an = a0; nxt = p0;
  }
  u32 cmask = (u32)__ballot(nxt != 0);

  const size_t eb = (size_t)b * 32 + k;        // + t*2048
  const size_t tb = (size_t)b * 16384 + k;     // + t*32
  float e1 = em[eb + 1 * 2048], e2 = em[eb + 2 * 2048];
  float e3 = em[eb + 3 * 2048], e4 = em[eb + 4 * 2048];
  int g1 = 1, g2 = 1, g3 = 1, g4 = 1;
  if (isnum) {
    g1 = tgt[tb + 1 * 32]; g2 = tgt[tb + 2 * 32];
    g3 = tgt[tb + 3 * 32]; g4 = tgt[tb + 4 * 32];
  }

  auto step = [&](float e_raw, int nx) {
    const u32 cm = cmask >> j0;
    float vv[16];
#pragma unroll
    for (int j = 0; j < 16; ++j) {
      const float a = __shfl(an, j0 + j);            // alpha[j0+j], prev step
      float t_ = tr[j];
      if (isnum && ((((cm >> j) & 1u) == 0u) || nx == 0)) t_ = IMPOSSIBLE;
      vv[j] = a + t_;
    }
    const float m0 = fmaxf(fmaxf(fmaxf(vv[0], vv[1]), fmaxf(vv[2], vv[3])),
                           fmaxf(fmaxf(vv[4], vv[5]), fmaxf(vv[6], vv[7])));
    const float m1 = fmaxf(fmaxf(fmaxf(vv[8], vv[9]), fmaxf(vv[10], vv[11])),
                           fmaxf(fmaxf(vv[12], vv[13]), fmaxf(vv[14], vv[15])));
    const float m = fmaxf(m0, m1);                   // fmax tree: exact
    float ss = 0.f;
#pragma unroll
    for (int j = 0; j < 16; ++j) ss += __expf(vv[j] - m);   // same order as R7
    const float m2 = __shfl_xor(m, 32);
    const float s2 = __shfl_xor(ss, 32);
    const float M = fmaxf(m, m2);
    const float S = ss * __expf(m - M) + s2 * __expf(m2 - M);
    const float e = (isnum && nx == 0) ? IMPOSSIBLE : e_raw;
    an = M + __logf(S) + e;
    nxt = nx;
    if (isnum) cmask = (u32)__ballot(nx != 0);
  };

#pragma unroll 1
  for (int t = 1; t <= 505; t += 4) {                // steps t..t+3
    const int t7 = (t + 7 < 512) ? (t + 7) : 511;    // clamp last prefetch
    const float n1 = em[eb + (size_t)(t + 4) * 2048];
    const float n2 = em[eb + (size_t)(t + 5) * 2048];
    const float n3 = em[eb + (size_t)(t + 6) * 2048];
    const float n4 = em[eb + (size_t)t7 * 2048];
    int h1 = 1, h2 = 1, h3 = 1, h4 = 1;
    if (isnum) {
      h1 = tgt[tb + (size_t)(t + 4) * 32]; h2 = tgt[tb + (size_t)(t + 5) * 32];
      h3 = tgt[tb + (size_t)(t + 6) * 32]; h4 = tgt[tb + (size_t)t7 * 32];
    }
    step(e1, g1); step(e2, g2); step(e3, g3); step(e4, g4);
    e1 = n1; e2 = n2; e3 = n3; e4 = n4;
    g1 = h1; g2 = h2; g3 = h3; g4 = h4;
  }
  step(e1, g1); step(e2, g2); step(e3, g3);          // t = 509, 510, 511

  float x;
  if (!isnum) {
    x = an + ent[k];
  } else {
    const float et = ent[k] * (float)nxt;
    x = an + ((et == 0.f) ? IMPOSSIBLE : et);
  }
  float m = x;
#pragma unroll
  for (int o = 1; o < 32; o <<= 1) m = fmaxf(m, __shfl_xor(m, o));
  float ss = __expf(x - m);
#pragma unroll
  for (int o = 1; o < 32; o <<= 1) ss += __shfl_xor(ss, o);
  if (lane == 0) {
    const float rr = m + __logf(ss);
    atomicAdd(out, isnum ? -rr : rr);
  }
}

// ---------------------------------------------------------------------------
extern "C" void kernel_launch(void* const* d_in, const int* in_sizes, int n_in,
                              void* d_out, int out_size, void* d_ws, size_t ws_size,
                              hipStream_t stream) {
  (void)in_sizes; (void)n_in; (void)out_size; (void)ws_size;
  const int* sents = (const int*)d_in[0];
  const int* tgt = (const int*)d_in[2];
  const float* emb = (const float*)d_in[3];
  const float* Wif = (const float*)d_in[4];
  const float* Whf = (const float*)d_in[5];
  const float* bf_ = (const float*)d_in[6];
  const float* Wib = (const float*)d_in[7];
  const float* Whb = (const float*)d_in[8];
  const float* bb_ = (const float*)d_in[9];
  const float* Wo = (const float*)d_in[10];
  const float* bo = (const float*)d_in[11];
  const float* stt = (const float*)d_in[12];
  const float* ent = (const float*)d_in[13];
  const float* trans = (const float*)d_in[14];
  float* out = (float*)d_out;

  char* ws = (char*)d_ws;
  u16* x2 = (u16*)ws;                          // 16777216 B
  u16* H2 = (u16*)(ws + 16777216ull);          // 67108864 B (blocked)
  float* em = (float*)(ws + 83886080ull);      //  4194304 B

  k_prep<<<dim3(16896), dim3(256), 0, stream>>>(sents, emb, x2, (u32*)H2, out);
  k_lstm<<<dim3(256), dim3(256), 0, stream>>>(Whf, Whb, Wif, Wib, bf_, bb_, x2, H2);
  k_emproj<<<dim3(512), dim3(256), 0, stream>>>(H2, Wo, bo, em);
  k_crf<<<dim3(128), dim3(64), 0, stream>>>(em, tgt, trans, stt, ent, out);
}

// Round 8
// 1462.028 us; speedup vs baseline: 1.3278x; 1.1336x over previous
//
#include <hip/hip_runtime.h>

// BiLSTM + partial-CRF loss, MI355X (gfx950).
// R15: scope fix. SC1:SC0 on gfx9xx loads is a 2-bit SCOPE field
// (0=CU,1=SE,2=device,3=system). R11-R14's asm polls used "sc0 sc1" =
// SYSTEM scope -> bypassed the MALL and read HBM every poll (~900cy);
// counter-proof: FETCH_SIZE carried a constant ~67MB = sizeof(H2) term in
// every canary round. R15 polls with "sc1" (DEVICE scope -> MALL-coherent,
// the same point the agent h-stores commit to). Fallback guard: 8 fast sc1
// retries, then the R11-proven sc0 sc1 loop (budget 4096 -> NaN-visible
// fail) -- correctness never depends on the sc1 path seeing the stores.
// Step structure is R11-verbatim (head-issued polls, two __syncthreads,
// single pre4; R14's prewarm/probe deleted -- prewarm ADDED 29MB HBM).
// Fill change (independent dispatch): canary = 0x7F7F7F7F (bf16 0x7F7F ~
// 3.4e38, unreachable for |h|<1), byte-repeating -> hipMemsetAsync(H2,0x7F)
// replaces the 16384-block fill kernel (suspected ~200us of the "rest" gap);
// out zeroed by hipMemsetAsync as well. k_embed standalone again.
// k_crf: R8's register-resident rewrite (validated, absmax 0).
//
// Sizes: B=64, L=512, V=50000, E=256, H=512, T=32.
// Workspace (~84 MiB):
//   x2   bf16 [512*64][256]                16777216 B @ 0
//   H2   bf16 blocked [t][d][g][s][256]    67108864 B @ 16777216
//   em   f32  [512*64][32]                  4194304 B @ 83886080

#define IMPOSSIBLE -10000.0f
#define CANARY 0x7F7F7F7Fu

typedef __attribute__((ext_vector_type(8))) short bf16x8;
typedef __attribute__((ext_vector_type(4))) float f32x4;
typedef __attribute__((ext_vector_type(4))) unsigned int u32x4;
typedef unsigned int u32;
typedef unsigned short u16;

__device__ __forceinline__ u16 f2b(float f) {           // fp32 -> bf16 (RNE)
  union { float f; u32 u; } v; v.f = f;
  return (u16)((v.u + 0x7fffu + ((v.u >> 16) & 1u)) >> 16);
}
__device__ __forceinline__ float sigm(float x) { return 1.0f / (1.0f + __expf(-x)); }
__device__ __forceinline__ float tanh_f(float x) { return 1.0f - 2.0f / (__expf(2.0f * x) + 1.0f); }

__device__ __forceinline__ u32 can4(const u32x4& q) {
  return (u32)(q[0] == CANARY) | (u32)(q[1] == CANARY) |
         (u32)(q[2] == CANARY) | (u32)(q[3] == CANARY);
}

// ---------------------------------------------------------------------------
// x2[t*64+b][e] = bf16(emb[sents[b][t]][e]).  One block per t.
__global__ __launch_bounds__(256) void k_embed(
    const int* __restrict__ sents, const float* __restrict__ emb,
    u16* __restrict__ x2) {
  __shared__ int tok[64];
  const int tid = threadIdx.x, t = blockIdx.x;
  if (tid < 64) tok[tid] = sents[tid * 512 + t];
  __syncthreads();
#pragma unroll
  for (int i = 0; i < 16; ++i) {
    const int v = i * 256 + tid;          // float4 index
    const int row = v >> 6, ke = (v & 63) * 4;
    const float4 f = *(const float4*)(emb + (size_t)tok[row] * 256 + ke);
    ushort4 s; s.x = f2b(f.x); s.y = f2b(f.y); s.z = f2b(f.z); s.w = f2b(f.w);
    *(ushort4*)&x2[((size_t)t * 64 + row) * 256 + ke] = s;
  }
}

// ---------------------------------------------------------------------------
// Persistent BiLSTM. 256 wgs x 256 thr, 1 wg/CU. group r=wid&7 -> (d=r>>2,
// g=r&3); slice s=wid>>3 (j0=s*16). Wave wv owns K-quarter for ALL 4 gates.
// Per step (R11 order): plain x loads + sc1 poll burst -> x MFMAs (overlap
// flight) -> tied vmcnt(0) + canary check (8 fast sc1 retries, then proven
// sc0sc1 guard) -> h MFMAs -> sync -> ds_write pre4 -> sync -> reduce +
// gates -> packed agent h store (no drain, no flag).
__global__ __launch_bounds__(256, 1) void k_lstm(
    const float* __restrict__ Whf, const float* __restrict__ Whb,
    const float* __restrict__ Wif, const float* __restrict__ Wib,
    const float* __restrict__ bf_, const float* __restrict__ bb_,
    const u16* __restrict__ x2, u16* __restrict__ H2) {
  __shared__ float pre4[4096];          // [wv][gate][kh][lm][rr]
  const int tid = threadIdx.x, wid = blockIdx.x;
  const int r = wid & 7, d = r >> 2, g = r & 3, s = wid >> 3;
  const int b0 = g * 16, j0 = s * 16;
  const float* __restrict__ Whh = d ? Whb : Whf;
  const float* __restrict__ Wih = d ? Wib : Wif;
  const float* __restrict__ bias = d ? bb_ : bf_;
  const int wv = tid >> 6, lane = tid & 63, lm = lane & 15, kh = lane >> 4;
  const int bl = tid >> 4, jj = tid & 15;

  // ---- weight fragments: B[k][n], n=lane&15, k = kh*8+j + 32*kt + wv*Kq ----
  bf16x8 wih_f[8], whh_f[16];
#pragma unroll
  for (int gg = 0; gg < 4; ++gg) {
    const float* wp = Wih + (size_t)(gg * 512 + j0 + lm) * 256 + wv * 64;
#pragma unroll
    for (int kt = 0; kt < 2; ++kt) {
      bf16x8 f;
#pragma unroll
      for (int j = 0; j < 8; ++j) f[j] = (short)f2b(wp[kt * 32 + kh * 8 + j]);
      wih_f[gg * 2 + kt] = f;
    }
    const float* wq = Whh + (size_t)(gg * 512 + j0 + lm) * 512 + wv * 128;
#pragma unroll
    for (int kt = 0; kt < 4; ++kt) {
      bf16x8 f;
#pragma unroll
      for (int j = 0; j < 8; ++j) f[j] = (short)f2b(wq[kt * 32 + kh * 8 + j]);
      whh_f[gg * 4 + kt] = f;
    }
  }
  const float b_i = bias[0 * 512 + j0 + jj];
  const float b_f = bias[1 * 512 + j0 + jj];
  const float b_g = bias[2 * 512 + j0 + jj];
  const float b_o = bias[3 * 512 + j0 + jj];

  float c = 0.f;
  const f32x4 z = {0.f, 0.f, 0.f, 0.f};
#pragma unroll 1
  for (int it = 0; it < 512; ++it) {
    const int tt = d ? (511 - it) : it;
    // x a-frags (K-quarter): issue now, land during the poll
    bf16x8 xa[2];
    {
      const u16* xp = x2 + ((size_t)tt * 64 + b0 + lm) * 256 + wv * 64 + kh * 8;
      xa[0] = *(const bf16x8*)xp;
      xa[1] = *(const bf16x8*)(xp + 32);
    }
    u32x4 q0, q1, q2, q3;
    const u32 *p0 = nullptr, *p1 = nullptr, *p2 = nullptr, *p3 = nullptr;
    if (it > 0) {
      const int tp = d ? (tt + 1) : (tt - 1);
      const size_t tb2 = (((size_t)tp * 2 + d) * 4 + g) * 32;
      const int fo = lm * 16 + (kh & 1) * 8;
      p0 = (const u32*)(H2 + (tb2 + wv * 8 + 0 + (kh >> 1)) * 256 + fo);
      p1 = (const u32*)(H2 + (tb2 + wv * 8 + 2 + (kh >> 1)) * 256 + fo);
      p2 = (const u32*)(H2 + (tb2 + wv * 8 + 4 + (kh >> 1)) * 256 + fo);
      p3 = (const u32*)(H2 + (tb2 + wv * 8 + 6 + (kh >> 1)) * 256 + fo);
      // DEVICE-scope poll burst (sc1): coherent at MALL, no HBM round trip
      asm volatile(
          "global_load_dwordx4 %0, %4, off sc1\n\t"
          "global_load_dwordx4 %1, %5, off sc1\n\t"
          "global_load_dwordx4 %2, %6, off sc1\n\t"
          "global_load_dwordx4 %3, %7, off sc1"
          : "=&v"(q0), "=&v"(q1), "=&v"(q2), "=&v"(q3)
          : "v"(p0), "v"(p1), "v"(p2), "v"(p3)
          : "memory");
    }
    f32x4 accg[4] = {z, z, z, z};
    // x MFMAs fill the poll flight time
#pragma unroll
    for (int gg = 0; gg < 4; ++gg)
#pragma unroll
      for (int kt = 0; kt < 2; ++kt)
        accg[gg] = __builtin_amdgcn_mfma_f32_16x16x32_bf16(xa[kt], wih_f[gg * 2 + kt], accg[gg], 0, 0, 0);
    if (it > 0) {
      // tied wait: q regs flow through the asm -> check can't hoist above it
      asm volatile("s_waitcnt vmcnt(0)"
                   : "+v"(q0), "+v"(q1), "+v"(q2), "+v"(q3) :: "memory");
      u32 anybad = can4(q0) | can4(q1) | can4(q2) | can4(q3);
      int fast = 8;         // fast tier: device-scope re-polls
      while (__any(anybad != 0) && --fast) {
        asm volatile(
            "global_load_dwordx4 %0, %4, off sc1\n\t"
            "global_load_dwordx4 %1, %5, off sc1\n\t"
            "global_load_dwordx4 %2, %6, off sc1\n\t"
            "global_load_dwordx4 %3, %7, off sc1\n\t"
            "s_waitcnt vmcnt(0)"
            : "=&v"(q0), "=&v"(q1), "=&v"(q2), "=&v"(q3)
            : "v"(p0), "v"(p1), "v"(p2), "v"(p3)
            : "memory");
        anybad = can4(q0) | can4(q1) | can4(q2) | can4(q3);
      }
      if (__any(anybad != 0)) {
        // guard tier: R11-proven system-scope loop; on exhaust canary NaNs
        // propagate -> absmax fail (visible, not a hang)
        int bud = 4096;
        do {
          asm volatile(
              "global_load_dwordx4 %0, %4, off sc0 sc1\n\t"
              "global_load_dwordx4 %1, %5, off sc0 sc1\n\t"
              "global_load_dwordx4 %2, %6, off sc0 sc1\n\t"
              "global_load_dwordx4 %3, %7, off sc0 sc1\n\t"
              "s_waitcnt vmcnt(0)"
              : "=&v"(q0), "=&v"(q1), "=&v"(q2), "=&v"(q3)
              : "v"(p0), "v"(p1), "v"(p2), "v"(p3)
              : "memory");
          anybad = can4(q0) | can4(q1) | can4(q2) | can4(q3);
        } while (__any(anybad != 0) && --bud);
      }
      union { u32x4 q; bf16x8 v; } c0, c1, c2, c3;
      c0.q = q0; c1.q = q1; c2.q = q2; c3.q = q3;
#pragma unroll
      for (int gg = 0; gg < 4; ++gg) {
        accg[gg] = __builtin_amdgcn_mfma_f32_16x16x32_bf16(c0.v, whh_f[gg * 4 + 0], accg[gg], 0, 0, 0);
        accg[gg] = __builtin_amdgcn_mfma_f32_16x16x32_bf16(c1.v, whh_f[gg * 4 + 1], accg[gg], 0, 0, 0);
        accg[gg] = __builtin_amdgcn_mfma_f32_16x16x32_bf16(c2.v, whh_f[gg * 4 + 2], accg[gg], 0, 0, 0);
        accg[gg] = __builtin_amdgcn_mfma_f32_16x16x32_bf16(c3.v, whh_f[gg * 4 + 3], accg[gg], 0, 0, 0);
      }
    }
    __syncthreads();        // WAR: prior step's pre4 reads complete
    // partials -> LDS, one ds_write_b128 per gate (layout [wv][g][kh][lm][rr])
#pragma unroll
    for (int gg = 0; gg < 4; ++gg)
      *(f32x4*)&pre4[wv * 1024 + gg * 256 + kh * 64 + lm * 4] = accg[gg];
    __syncthreads();        // RAW: partials visible
    const int off = (bl >> 2) * 64 + jj * 4 + (bl & 3);
    float pi = b_i, pf = b_f, pg = b_g, po = b_o;
#pragma unroll
    for (int w4 = 0; w4 < 4; ++w4) {
      pi += pre4[w4 * 1024 + 0   + off];
      pf += pre4[w4 * 1024 + 256 + off];
      pg += pre4[w4 * 1024 + 512 + off];
      po += pre4[w4 * 1024 + 768 + off];
    }
    c = sigm(pf) * c + sigm(pi) * tanh_f(pg);
    const float h = sigm(po) * tanh_f(c);
    const float hq = __shfl_xor(h, 1);
    if ((tid & 1) == 0) {   // block element = tid; pack pair -> u32, agent store
      const u32 pk = (u32)f2b(h) | ((u32)f2b(hq) << 16);
      u32* hp2 = (u32*)H2 + ((((size_t)tt * 2 + d) * 4 + g) * 32 + s) * 128 + (tid >> 1);
      __hip_atomic_store(hp2, pk, __ATOMIC_RELAXED, __HIP_MEMORY_SCOPE_AGENT);
    }
    // no drain, no flag: consumers poll the data dwords themselves
  }
}

// ---------------------------------------------------------------------------
// em[t*64+b][tag] = [hf|hb] @ W_out^T + b_out. One block per t; blocked-H2 A.
__global__ __launch_bounds__(256) void k_emproj(
    const u16* __restrict__ H2, const float* __restrict__ Wo,
    const float* __restrict__ bo, float* __restrict__ em) {
  __shared__ u16 Wl[32 * 1024];
  const int tid = threadIdx.x, mb = blockIdx.x;
  const int wv = tid >> 6, lane = tid & 63, lm = lane & 15, kh = lane >> 4;
#pragma unroll
  for (int i = 0; i < 32; ++i) {        // stage Wo 32x1024 f32 -> bf16, rotated
    const int row = i, k = tid * 4;
    const float4 f = *(const float4*)(Wo + (size_t)row * 1024 + k);
    ushort4 s; s.x = f2b(f.x); s.y = f2b(f.y); s.z = f2b(f.z); s.w = f2b(f.w);
    *(ushort4*)&Wl[row * 1024 + ((k + 8 * row) & 1023)] = s;
  }
  __syncthreads();
  const f32x4 z = {0.f, 0.f, 0.f, 0.f};
  f32x4 acc[2] = {z, z};
#pragma unroll 2
  for (int kt = 0; kt < 32; ++kt) {     // k-global = kt*32 + kh*8 + j
    const int dd = kt >> 4;
    const int sG = (kt & 15) * 2 + (kh >> 1);
    const u16* ap = H2 + ((((size_t)mb * 2 + dd) * 4 + wv) * 32 + sG) * 256 + lm * 16 + (kh & 1) * 8;
    const bf16x8 a = *(const bf16x8*)ap;
#pragma unroll
    for (int ni = 0; ni < 2; ++ni) {
      const int row = ni * 16 + lm;
      const bf16x8 b = *(const bf16x8*)&Wl[row * 1024 + ((kt * 32 + kh * 8 + 8 * row) & 1023)];
      acc[ni] = __builtin_amdgcn_mfma_f32_16x16x32_bf16(a, b, acc[ni], 0, 0, 0);
    }
  }
#pragma unroll
  for (int ni = 0; ni < 2; ++ni) {
    const int n = ni * 16 + lm;
    const float bv = bo[n];
#pragma unroll
    for (int rr = 0; rr < 4; ++rr) {
      const int m = mb * 64 + wv * 16 + kh * 4 + rr;
      em[(size_t)m * 32 + n] = acc[ni][rr] + bv;
    }
  }
}

// ---------------------------------------------------------------------------
// CRF forward scans, fp32. One wave per (b, which). Register-resident: trans
// rows in 16 regs, alpha propagated via __shfl (no LDS, no barriers),
// possible-tag mask as __ballot bitmask, em/tgt 4-step prefetch pipeline.
// Same summation order as the LDS version => identical numerics.
__global__ __launch_bounds__(64) void k_crf(
    const float* __restrict__ em, const int* __restrict__ tgt,
    const float* __restrict__ trans, const float* __restrict__ stt,
    const float* __restrict__ ent, float* __restrict__ out) {
  const int lane = threadIdx.x;
  const int b = blockIdx.x >> 1;
  const int isnum = blockIdx.x & 1;
  const int k = lane & 31, j0 = (lane >> 5) * 16;
  float tr[16];
#pragma unroll
  for (int j = 0; j < 16; ++j) tr[j] = trans[(j0 + j) * 32 + k];

  float an; int nxt;
  {
    float a0 = stt[k] + em[(size_t)b * 32 + k];
    int p0 = 1;
    if (isnum) { p0 = tgt[((size_t)b * 512) * 32 + k]; if (p0 == 0) a0 = IMPOSSIBLE; }
    an = a0; nxt = p0;
  }
  u32 cmask = (u32)__ballot(nxt != 0);

  const size_t eb = (size_t)b * 32 + k;        // + t*2048
  const size_t tb = (size_t)b * 16384 + k;     // + t*32
  float e1 = em[eb + 1 * 2048], e2 = em[eb + 2 * 2048];
  float e3 = em[eb + 3 * 2048], e4 = em[eb + 4 * 2048];
  int g1 = 1, g2 = 1, g3 = 1, g4 = 1;
  if (isnum) {
    g1 = tgt[tb + 1 * 32]; g2 = tgt[tb + 2 * 32];
    g3 = tgt[tb + 3 * 32]; g4 = tgt[tb + 4 * 32];
  }

  auto step = [&](float e_raw, int nx) {
    const u32 cm = cmask >> j0;
    float vv[16];
#pragma unroll
    for (int j = 0; j < 16; ++j) {
      const float a = __shfl(an, j0 + j);            // alpha[j0+j], prev step
      float t_ = tr[j];
      if (isnum && ((((cm >> j) & 1u) == 0u) || nx == 0)) t_ = IMPOSSIBLE;
      vv[j] = a + t_;
    }
    const float m0 = fmaxf(fmaxf(fmaxf(vv[0], vv[1]), fmaxf(vv[2], vv[3])),
                           fmaxf(fmaxf(vv[4], vv[5]), fmaxf(vv[6], vv[7])));
    const float m1 = fmaxf(fmaxf(fmaxf(vv[8], vv[9]), fmaxf(vv[10], vv[11])),
                           fmaxf(fmaxf(vv[12], vv[13]), fmaxf(vv[14], vv[15])));
    const float m = fmaxf(m0, m1);                   // fmax tree: exact
    float ss = 0.f;
#pragma unroll
    for (int j = 0; j < 16; ++j) ss += __expf(vv[j] - m);   // same order as R7
    const float m2 = __shfl_xor(m, 32);
    const float s2 = __shfl_xor(ss, 32);
    const float M = fmaxf(m, m2);
    const float S = ss * __expf(m - M) + s2 * __expf(m2 - M);
    const float e = (isnum && nx == 0) ? IMPOSSIBLE : e_raw;
    an = M + __logf(S) + e;
    nxt = nx;
    if (isnum) cmask = (u32)__ballot(nx != 0);
  };

#pragma unroll 1
  for (int t = 1; t <= 505; t += 4) {                // steps t..t+3
    const int t7 = (t + 7 < 512) ? (t + 7) : 511;    // clamp last prefetch
    const float n1 = em[eb + (size_t)(t + 4) * 2048];
    const float n2 = em[eb + (size_t)(t + 5) * 2048];
    const float n3 = em[eb + (size_t)(t + 6) * 2048];
    const float n4 = em[eb + (size_t)t7 * 2048];
    int h1 = 1, h2 = 1, h3 = 1, h4 = 1;
    if (isnum) {
      h1 = tgt[tb + (size_t)(t + 4) * 32]; h2 = tgt[tb + (size_t)(t + 5) * 32];
      h3 = tgt[tb + (size_t)(t + 6) * 32]; h4 = tgt[tb + (size_t)t7 * 32];
    }
    step(e1, g1); step(e2, g2); step(e3, g3); step(e4, g4);
    e1 = n1; e2 = n2; e3 = n3; e4 = n4;
    g1 = h1; g2 = h2; g3 = h3; g4 = h4;
  }
  step(e1, g1); step(e2, g2); step(e3, g3);          // t = 509, 510, 511

  float x;
  if (!isnum) {
    x = an + ent[k];
  } else {
    const float et = ent[k] * (float)nxt;
    x = an + ((et == 0.f) ? IMPOSSIBLE : et);
  }
  float m = x;
#pragma unroll
  for (int o = 1; o < 32; o <<= 1) m = fmaxf(m, __shfl_xor(m, o));
  float ss = __expf(x - m);
#pragma unroll
  for (int o = 1; o < 32; o <<= 1) ss += __shfl_xor(ss, o);
  if (lane == 0) {
    const float rr = m + __logf(ss);
    atomicAdd(out, isnum ? -rr : rr);
  }
}

// ---------------------------------------------------------------------------
extern "C" void kernel_launch(void* const* d_in, const int* in_sizes, int n_in,
                              void* d_out, int out_size, void* d_ws, size_t ws_size,
                              hipStream_t stream) {
  (void)in_sizes; (void)n_in; (void)ws_size;
  const int* sents = (const int*)d_in[0];
  const int* tgt = (const int*)d_in[2];
  const float* emb = (const float*)d_in[3];
  const float* Wif = (const float*)d_in[4];
  const float* Whf = (const float*)d_in[5];
  const float* bf_ = (const float*)d_in[6];
  const float* Wib = (const float*)d_in[7];
  const float* Whb = (const float*)d_in[8];
  const float* bb_ = (const float*)d_in[9];
  const float* Wo = (const float*)d_in[10];
  const float* bo = (const float*)d_in[11];
  const float* stt = (const float*)d_in[12];
  const float* ent = (const float*)d_in[13];
  const float* trans = (const float*)d_in[14];
  float* out = (float*)d_out;

  char* ws = (char*)d_ws;
  u16* x2 = (u16*)ws;                          // 16777216 B
  u16* H2 = (u16*)(ws + 16777216ull);          // 67108864 B (blocked)
  float* em = (float*)(ws + 83886080ull);      //  4194304 B

  // canary fill (0x7F bytes -> dword 0x7F7F7F7F) + out=0 via driver blit
  hipMemsetAsync(H2, 0x7F, 67108864ull, stream);
  hipMemsetAsync(d_out, 0, (size_t)out_size, stream);
  k_embed<<<dim3(512), dim3(256), 0, stream>>>(sents, emb, x2);
  k_lstm<<<dim3(256), dim3(256), 0, stream>>>(Whf, Whb, Wif, Wib, bf_, bb_, x2, H2);
  k_emproj<<<dim3(512), dim3(256), 0, stream>>>(H2, Wo, bo, em);
  k_crf<<<dim3(128), dim3(64), 0, stream>>>(em, tgt, trans, stt, ent, out);
}